// Round 4
// baseline (325.773 us; speedup 1.0000x reference)
//
#include <hip/hip_runtime.h>
#include <stdint.h>

// Problem constants
#define DIM    1024
#define RANK   16
#define M_TOT  8192          // 2*4096 rows of x
#define N_TOT  3072          // 3*DIM output features
#define K_TOT  1024

// GEMM tiling: block = 128x128, 4 waves (2x2), wave tile 64x64 (acc 4x4)
#define BM 128
#define BN 128

typedef __attribute__((ext_vector_type(8))) short  s8v;   // 8 x bf16 (raw bits)
typedef __attribute__((ext_vector_type(4))) float  f4v;   // MFMA acc

__device__ __forceinline__ unsigned short f2bf(float f) {
    union { float f; unsigned int u; } v; v.f = f;
    unsigned int u = v.u;
    u += 0x7FFFu + ((u >> 16) & 1u);   // round-to-nearest-even
    return (unsigned short)(u >> 16);
}

// ---------------- Kernel 1: fused prep ----------------
// blocks [0, 8192):     x fp32 -> bf16 (float4 -> ushort4)
// blocks [8192, 11264): fold LoRA into W, fp32 -> bf16
__global__ void prep(const float4* __restrict__ x, ushort4* __restrict__ xb,
                     const float* __restrict__ W,
                     const float* __restrict__ Aq, const float* __restrict__ Bq,
                     const float* __restrict__ Ak, const float* __restrict__ Bk,
                     const float* __restrict__ Av, const float* __restrict__ Bv,
                     const float* __restrict__ alpha_p,
                     unsigned short* __restrict__ Wb) {
    const int tid = threadIdx.x;
    if (blockIdx.x < 8192) {
        int i = blockIdx.x * 256 + tid;      // n4 = 2097152 = 8192*256 exactly
        float4 v = x[i];
        ushort4 o;
        o.x = f2bf(v.x); o.y = f2bf(v.y); o.z = f2bf(v.z); o.w = f2bf(v.w);
        xb[i] = o;
    } else {
        const int o    = blockIdx.x - 8192;  // 0..3071
        const int sel  = o >> 10;            // 0=q 1=k 2=v
        const int orow = o & 1023;
        const float* Am = (sel == 0) ? Aq : (sel == 1) ? Ak : Av;  // [RANK, DIM]
        const float* Bm = (sel == 0) ? Bq : (sel == 1) ? Bk : Bv;  // [DIM, RANK]

        __shared__ float sb[RANK];
        if (tid < RANK) sb[tid] = alpha_p[0] * Bm[orow * RANK + tid];
        __syncthreads();

        for (int d = tid; d < DIM; d += 256) {
            float acc = W[o * DIM + d];
            #pragma unroll
            for (int r = 0; r < RANK; ++r)
                acc += sb[r] * Am[r * DIM + d];
            Wb[o * DIM + d] = f2bf(acc);
        }
    }
}

// ---------------- Kernel 2: barrier-free no-LDS MFMA GEMM ----------------
// C = Xb * Wb^T + bias.  Xb: [M,K] bf16 rm; Wb: [N,K] bf16 rm.
// Each wave loads its own A/B fragments straight from global memory:
// fragment for mfma_16x16x32 = lane(l): row l&15, k (l>>4)*8, 8 contiguous
// bf16 -> one global_load_dwordx4, lanes {l,l+16,l+32,l+48} share a 64-B line
// (16 lines/load, fully coalesced). LDS only bought 2x reuse (L1 now catches
// the duplicate: 2 waves/CU-block share each frag) at the cost of the
// 2-barrier bulk-synchronous drain that pinned rounds 1-3 at ~107 us.
// Zero __syncthreads, zero LDS; register double-buffer, 16 loads in flight.
__global__ __launch_bounds__(256, 3)
void gemm_bt(const unsigned short* __restrict__ Xb,
             const unsigned short* __restrict__ Wb,
             const float* __restrict__ bias,
             float* __restrict__ out) {
    const int tid  = threadIdx.x;
    const int wave = tid >> 6;       // 0..3
    const int lane = tid & 63;
    const int l15  = lane & 15;
    const int lq   = lane >> 4;      // 0..3
    const int wr   = wave >> 1;      // wave row quadrant (0..1)
    const int wc   = wave & 1;       // wave col quadrant (0..1)

    const int bm = blockIdx.x;       // 0..63   (M tiles)
    const int bn = blockIdx.y;       // 0..23   (N tiles)

    // Per-fragment base pointers (k advances via element offset)
    const unsigned short* ap[4];
    const unsigned short* bp[4];
    #pragma unroll
    for (int i = 0; i < 4; ++i) {
        ap[i] = Xb + (size_t)(bm * BM + wr * 64 + i * 16 + l15) * K_TOT + lq * 8;
        bp[i] = Wb + (size_t)(bn * BN + wc * 64 + i * 16 + l15) * K_TOT + lq * 8;
    }

    s8v a0[4], b0[4], a1[4], b1[4];
    #pragma unroll
    for (int i = 0; i < 4; ++i) {
        a0[i] = *(const s8v*)(ap[i]);
        b0[i] = *(const s8v*)(bp[i]);
    }

    f4v acc[4][4] = {};

    for (int kk = 0; kk < K_TOT; kk += 64) {
        // prefetch k-step kk+32 while computing kk
        const int k1 = kk + 32;
        #pragma unroll
        for (int i = 0; i < 4; ++i) {
            a1[i] = *(const s8v*)(ap[i] + k1);
            b1[i] = *(const s8v*)(bp[i] + k1);
        }
        #pragma unroll
        for (int i = 0; i < 4; ++i)
            #pragma unroll
            for (int j = 0; j < 4; ++j)
                acc[i][j] = __builtin_amdgcn_mfma_f32_16x16x32_bf16(
                    a0[i], b0[j], acc[i][j], 0, 0, 0);

        // prefetch k-step kk+64 (wraps to 0 on last iter: harmless reload)
        const int k2 = (kk + 64) & (K_TOT - 1);
        #pragma unroll
        for (int i = 0; i < 4; ++i) {
            a0[i] = *(const s8v*)(ap[i] + k2);
            b0[i] = *(const s8v*)(bp[i] + k2);
        }
        #pragma unroll
        for (int i = 0; i < 4; ++i)
            #pragma unroll
            for (int j = 0; j < 4; ++j)
                acc[i][j] = __builtin_amdgcn_mfma_f32_16x16x32_bf16(
                    a1[i], b1[j], acc[i][j], 0, 0, 0);
    }

    // Epilogue: C/D layout col = lane&15, row = (lane>>4)*4 + reg  [m89]
    const int col_base = bn * BN + wc * 64;
    const int row_base = bm * BM + wr * 64 + lq * 4;
    #pragma unroll
    for (int j = 0; j < 4; ++j) {
        const int col = col_base + j * 16 + l15;
        const float bv = bias[col];
        #pragma unroll
        for (int i = 0; i < 4; ++i) {
            const int row = row_base + i * 16;
            #pragma unroll
            for (int r = 0; r < 4; ++r)
                out[(size_t)(row + r) * N_TOT + col] = acc[i][j][r] + bv;
        }
    }
}

extern "C" void kernel_launch(void* const* d_in, const int* in_sizes, int n_in,
                              void* d_out, int out_size, void* d_ws, size_t ws_size,
                              hipStream_t stream) {
    const float* x     = (const float*)d_in[0];   // [2,4096,1024]
    const float* W     = (const float*)d_in[1];   // [3072,1024]
    const float* b     = (const float*)d_in[2];   // [3072]
    const float* Aq    = (const float*)d_in[3];
    const float* Bq    = (const float*)d_in[4];
    const float* Ak    = (const float*)d_in[5];
    const float* Bk    = (const float*)d_in[6];
    const float* Av    = (const float*)d_in[7];
    const float* Bv    = (const float*)d_in[8];
    const float* alpha = (const float*)d_in[9];
    float* out = (float*)d_out;

    unsigned short* xb = (unsigned short*)d_ws;                                      // 16 MB
    unsigned short* Wb = (unsigned short*)((char*)d_ws + (size_t)M_TOT * K_TOT * 2); // +6 MB

    prep<<<8192 + N_TOT, 256, 0, stream>>>((const float4*)x, (ushort4*)xb,
                                           W, Aq, Bq, Ak, Bk, Av, Bv, alpha, Wb);

    dim3 grid(M_TOT / BM, N_TOT / BN);    // 64 x 24 = 1536 blocks
    gemm_bt<<<grid, 256, 0, stream>>>(xb, Wb, b, out);
}

// Round 5
// 254.837 us; speedup vs baseline: 1.2784x; 1.2784x over previous
//
#include <hip/hip_runtime.h>
#include <stdint.h>

// Problem constants
#define DIM    1024
#define RANK   16
#define M_TOT  8192          // 2*4096 rows of x
#define N_TOT  3072          // 3*DIM output features
#define K_TOT  1024

// GEMM tiling: block = 256(M) x 128(N), BK=64, 512 threads = 8 waves (4x2),
// wave tile 64x64 (acc 4x4 = 64 AGPR).
#define BM 256
#define BN 128
#define BK 64

typedef __attribute__((ext_vector_type(8))) short  s8v;   // 8 x bf16 (raw bits)
typedef __attribute__((ext_vector_type(4))) float  f4v;   // MFMA acc

__device__ __forceinline__ unsigned short f2bf(float f) {
    union { float f; unsigned int u; } v; v.f = f;
    unsigned int u = v.u;
    u += 0x7FFFu + ((u >> 16) & 1u);   // round-to-nearest-even
    return (unsigned short)(u >> 16);
}

// ---------------- Kernel 1: fused prep ----------------
// blocks [0, 8192):     x fp32 -> bf16 (float4 -> ushort4)
// blocks [8192, 11264): fold LoRA into W, fp32 -> bf16
__global__ void prep(const float4* __restrict__ x, ushort4* __restrict__ xb,
                     const float* __restrict__ W,
                     const float* __restrict__ Aq, const float* __restrict__ Bq,
                     const float* __restrict__ Ak, const float* __restrict__ Bk,
                     const float* __restrict__ Av, const float* __restrict__ Bv,
                     const float* __restrict__ alpha_p,
                     unsigned short* __restrict__ Wb) {
    const int tid = threadIdx.x;
    if (blockIdx.x < 8192) {
        int i = blockIdx.x * 256 + tid;      // n4 = 2097152 = 8192*256 exactly
        float4 v = x[i];
        ushort4 o;
        o.x = f2bf(v.x); o.y = f2bf(v.y); o.z = f2bf(v.z); o.w = f2bf(v.w);
        xb[i] = o;
    } else {
        const int o    = blockIdx.x - 8192;  // 0..3071
        const int sel  = o >> 10;            // 0=q 1=k 2=v
        const int orow = o & 1023;
        const float* Am = (sel == 0) ? Aq : (sel == 1) ? Ak : Av;  // [RANK, DIM]
        const float* Bm = (sel == 0) ? Bq : (sel == 1) ? Bk : Bv;  // [DIM, RANK]

        __shared__ float sb[RANK];
        if (tid < RANK) sb[tid] = alpha_p[0] * Bm[orow * RANK + tid];
        __syncthreads();

        for (int d = tid; d < DIM; d += 256) {
            float acc = W[o * DIM + d];
            #pragma unroll
            for (int r = 0; r < RANK; ++r)
                acc += sb[r] * Am[r * DIM + d];
            Wb[o * DIM + d] = f2bf(acc);
        }
    }
}

// ---------------- Kernel 2: bf16 MFMA GEMM, C = Xb * Wb^T + bias ----------------
// Empirical law from rounds 1-4: gemm time tracks MFMA-payload-per-barrier-event
// (r2: 128 MFMA/blk-iter -> 150us; r1: 256 -> 107us), nearly independent of
// occupancy. This round doubles payload again: 256x128 tile, 8 waves, 512
// MFMA per block-iter per 2 barriers, and raises arithmetic intensity to
// 87 FLOP per LDS-staged byte (from 65.5).
// LDS: fragment-ordered 1KB chunks (global_load_lds writes wave-uniform base
// + lane*16; lane l owns bytes [c*1024 + l*16)). A = 32 chunks, B = 16;
// each of 8 waves stages 6. ds_read_b128 conflict-free (verified 0 in r1-r3).
__global__ __launch_bounds__(512, 4)
void gemm_bt(const unsigned short* __restrict__ Xb,
             const unsigned short* __restrict__ Wb,
             const float* __restrict__ bias,
             float* __restrict__ out) {
    __shared__ __align__(16) unsigned short As[BM * BK];  // 32 KB, chunks 0..31
    __shared__ __align__(16) unsigned short Bs[BN * BK];  // 16 KB, chunks 0..15

    const int tid  = threadIdx.x;
    const int wave = tid >> 6;       // 0..7
    const int lane = tid & 63;
    const int l15  = lane & 15;
    const int lq   = lane >> 4;      // 0..3
    const int wr   = wave >> 1;      // 0..3  M quadrant (64 rows each)
    const int wc   = wave & 1;       // 0..1  N half (64 cols each)

    const int bm = blockIdx.x;       // 0..31  (M tiles of 256)
    const int bn = blockIdx.y;       // 0..23  (N tiles of 128)

    // Staging: 48 chunks total; wave stages q = wave*6 .. +5.
    // q < 32 -> A chunk q; q >= 32 -> B chunk q-32.
    // Chunk c: rows (c>>1)*16 + l15, k-cols (c&1)*32 + lq*8.
    const unsigned short* gptr[6];
    const unsigned short* lbase[6];   // wave-uniform LDS chunk base
    #pragma unroll
    for (int u = 0; u < 6; ++u) {
        const int q   = wave * 6 + u;        // 0..47
        const bool isA = (q < 32);
        const int c   = isA ? q : (q - 32);
        const int row = ((c >> 1) << 4) + l15;
        const int col = ((c & 1) << 5) + (lq << 3);
        gptr[u]  = isA ? (Xb + (size_t)(bm * BM + row) * K_TOT + col)
                       : (Wb + (size_t)(bn * BN + row) * K_TOT + col);
        lbase[u] = isA ? &As[c * 512] : &Bs[c * 512];
    }

    f4v acc[4][4] = {};

    for (int kk = 0; kk < K_TOT; kk += BK) {
        __syncthreads();   // all waves done reading LDS from prev iter
        #pragma unroll
        for (int u = 0; u < 6; ++u) {
            __builtin_amdgcn_global_load_lds(
                (const __attribute__((address_space(1))) void*)(gptr[u]),
                (__attribute__((address_space(3))) void*)(lbase[u]),
                16, 0, 0);
            gptr[u] += BK;
        }
        __syncthreads();   // staging landed

        const s8v* Avp = (const s8v*)As;
        const s8v* Bvp = (const s8v*)Bs;
        #pragma unroll
        for (int t = 0; t < 2; ++t) {          // two k-steps of 32 within BK=64
            s8v af[4], bf[4];
            #pragma unroll
            for (int i = 0; i < 4; ++i) {
                af[i] = Avp[((wr * 4 + i) * 2 + t) * 64 + lane];
                bf[i] = Bvp[((wc * 4 + i) * 2 + t) * 64 + lane];
            }
            #pragma unroll
            for (int i = 0; i < 4; ++i)
                #pragma unroll
                for (int j = 0; j < 4; ++j)
                    acc[i][j] = __builtin_amdgcn_mfma_f32_16x16x32_bf16(
                        af[i], bf[j], acc[i][j], 0, 0, 0);
        }
    }

    // Epilogue: C/D layout col = lane&15, row = (lane>>4)*4 + reg  [m89]
    const int col_base = bn * BN + wc * 64;
    const int row_base = bm * BM + wr * 64 + lq * 4;
    #pragma unroll
    for (int j = 0; j < 4; ++j) {
        const int col = col_base + j * 16 + l15;
        const float bv = bias[col];
        #pragma unroll
        for (int i = 0; i < 4; ++i) {
            const int row = row_base + i * 16;
            #pragma unroll
            for (int r = 0; r < 4; ++r)
                out[(size_t)(row + r) * N_TOT + col] = acc[i][j][r] + bv;
        }
    }
}

extern "C" void kernel_launch(void* const* d_in, const int* in_sizes, int n_in,
                              void* d_out, int out_size, void* d_ws, size_t ws_size,
                              hipStream_t stream) {
    const float* x     = (const float*)d_in[0];   // [2,4096,1024]
    const float* W     = (const float*)d_in[1];   // [3072,1024]
    const float* b     = (const float*)d_in[2];   // [3072]
    const float* Aq    = (const float*)d_in[3];
    const float* Bq    = (const float*)d_in[4];
    const float* Ak    = (const float*)d_in[5];
    const float* Bk    = (const float*)d_in[6];
    const float* Av    = (const float*)d_in[7];
    const float* Bv    = (const float*)d_in[8];
    const float* alpha = (const float*)d_in[9];
    float* out = (float*)d_out;

    unsigned short* xb = (unsigned short*)d_ws;                                      // 16 MB
    unsigned short* Wb = (unsigned short*)((char*)d_ws + (size_t)M_TOT * K_TOT * 2); // +6 MB

    prep<<<8192 + N_TOT, 256, 0, stream>>>((const float4*)x, (ushort4*)xb,
                                           W, Aq, Bq, Ak, Bk, Av, Bv, alpha, Wb);

    dim3 grid(M_TOT / BM, N_TOT / BN);    // 32 x 24 = 768 blocks
    gemm_bt<<<grid, 512, 0, stream>>>(xb, Wb, b, out);
}